// Round 6
// baseline (165.077 us; speedup 1.0000x reference)
//
#include <hip/hip_runtime.h>

#define HWSZ   10000
#define A_     9
#define C_     21
#define B_     8
#define M_     32
#define TPB    256
#define Q_     2500          // float4s per (b,a) slab (10000/4)
#define SUBS   10            // blocks per slab: ceil(2500/256)
#define BPI    (A_*SUBS)     // 90 blocks per image
#define P_     (B_*BPI)      // 720 blocks / partial slots
#define PROBE_ITERS 8

__device__ __forceinline__ float smooth_l1(float d) {
    float ad = fabsf(d);
    return ad < 1.f ? 0.5f * d * d : ad - 0.5f;
}

__device__ __forceinline__ float wave_red(float v) {
    #pragma unroll
    for (int o = 32; o; o >>= 1) v += __shfl_down(v, o);
    return v;
}

// constant-k float4 component select (folds after unroll; no scratch)
__device__ __forceinline__ float fc(const float4& v, int k) {
    return k == 0 ? v.x : k == 1 ? v.y : k == 2 ? v.z : v.w;
}

// Per-(b,a,q) work: accumulates into the 5 refs. Register-conscious pipeline:
// 10 cls loads in flight during decode+IoU, 11 more during LSE half A.
__device__ __forceinline__ void det_body(
    const float* __restrict__ cls, const float* __restrict__ reg,
    const float* __restrict__ anchors,
    const float4* sbox, const float* sarea, const int* slbl,
    int b, int a, int q,
    float& ce_pos, float& ce_neg, float& sl1, float& nposf, float& nnegf)
{
    // ---- issue anchors+reg + first 10 cls loads ----
    float4 an[4], rg[4];
    const float4* anch4 = (const float4*)anchors + (size_t)a * HWSZ + q * 4;
    #pragma unroll
    for (int k = 0; k < 4; ++k) an[k] = anch4[k];
    const float4* reg4 = (const float4*)reg + ((b * A_ + a) * 4) * Q_ + q;
    #pragma unroll
    for (int k = 0; k < 4; ++k) rg[k] = reg4[k * Q_];
    const float4* cls4 = (const float4*)cls + ((b * A_ + a) * C_) * Q_ + q;
    float4 bufA[10];
    #pragma unroll
    for (int j = 0; j < 10; ++j) bufA[j] = cls4[j * Q_];

    // ---- decode 4 anchors (waits anchors+reg; cls half A in flight) ----
    float aw[4], ah[4], acx[4], acy[4];
    float r0[4], r1[4], r2[4], r3[4];
    float dx1[4], dy1[4], dx2[4], dy2[4], ara[4];
    #pragma unroll
    for (int k = 0; k < 4; ++k) {
        float4 A = an[k];
        aw[k] = A.z - A.x; ah[k] = A.w - A.y;
        acx[k] = A.x + 0.5f * aw[k]; acy[k] = A.y + 0.5f * ah[k];
        r0[k] = fc(rg[0], k); r1[k] = fc(rg[1], k);
        r2[k] = fc(rg[2], k); r3[k] = fc(rg[3], k);
        float tx = r0[k] * 2.f - 1.f, ty = r1[k] * 2.f - 1.f;
        float cx = acx[k] + tx * aw[k] * 0.25f;
        float cy = acy[k] + ty * ah[k] * 0.25f;
        float w = aw[k] * __expf(r2[k]), h = ah[k] * __expf(r3[k]);
        dx1[k] = cx - 0.5f * w; dy1[k] = cy - 0.5f * h;
        dx2[k] = cx + 0.5f * w; dy2[k] = cy + 0.5f * h;
        ara[k] = w * h;
    }

    // ---- argmax IoU via cross-multiplication (exact, no div) ----
    float bi[4] = {-1.f, -1.f, -1.f, -1.f};
    float bu[4] = { 1.f,  1.f,  1.f,  1.f};
    int   bx_[4] = {0, 0, 0, 0};
    #pragma unroll 4
    for (int m = 0; m < M_; ++m) {
        float4 gb = sbox[m];
        float  am = sarea[m];
        #pragma unroll
        for (int k = 0; k < 4; ++k) {
            float lx = fmaxf(dx1[k], gb.x), ly = fmaxf(dy1[k], gb.y);
            float rx = fminf(dx2[k], gb.z), ry = fminf(dy2[k], gb.w);
            float iw = fmaxf(rx - lx, 0.f), ih = fmaxf(ry - ly, 0.f);
            float inter = iw * ih;
            float uni   = ara[k] + am - inter;
            bool  gt    = inter * bu[k] > bi[k] * uni;  // iou > best
            bi[k]  = gt ? inter : bi[k];
            bu[k]  = gt ? uni   : bu[k];
            bx_[k] = gt ? m     : bx_[k];
        }
    }

    // ---- thresholds, labels, encode + smooth-L1 (branchless) ----
    float posf[4], negf[4];
    int   lbl[4];
    #pragma unroll
    for (int k = 0; k < 4; ++k) {
        posf[k] = (bi[k] >= 0.25f * bu[k]) ? 1.f : 0.f;
        negf[k] = (bi[k] <  0.10f * bu[k]) ? 1.f : 0.f;
        lbl[k]  = slbl[bx_[k]];
        float4 gb = sbox[bx_[k]];
        float gw = gb.z - gb.x, gh = gb.w - gb.y;
        float gcx = gb.x + 0.5f * gw, gcy = gb.y + 0.5f * gh;
        float raw = __builtin_amdgcn_rcpf(aw[k]);
        float rah = __builtin_amdgcn_rcpf(ah[k]);
        float ttx = ((gcx - acx[k]) * 4.f * raw + 1.f) * 0.5f;
        float tty = ((gcy - acy[k]) * 4.f * rah + 1.f) * 0.5f;
        float ttw = __logf(gw * raw), tth = __logf(gh * rah);
        float s4 = smooth_l1(r0[k] - ttx) + smooth_l1(r1[k] - tty)
                 + smooth_l1(r2[k] - ttw) + smooth_l1(r3[k] - tth);
        sl1   += s4 * posf[k];
        nposf += posf[k];
        nnegf += negf[k];
    }

    // ---- issue cls half B, then process half A (max-free LSE) ----
    float4 bufB[11];
    #pragma unroll
    for (int j = 0; j < 11; ++j) bufB[j] = cls4[(10 + j) * Q_];

    float s[4], vlbl[4], v0[4];
    {
        float4 v = bufA[0];
        #pragma unroll
        for (int k = 0; k < 4; ++k) {
            float vk = fc(v, k);
            v0[k]   = vk;
            s[k]    = __expf(vk);
            vlbl[k] = (lbl[k] == 0) ? vk : 0.f;
        }
    }
    #pragma unroll
    for (int c = 1; c < 10; ++c) {
        float4 v = bufA[c];
        #pragma unroll
        for (int k = 0; k < 4; ++k) {
            float vk = fc(v, k);
            s[k] += __expf(vk);
            vlbl[k] = (lbl[k] == c) ? vk : vlbl[k];
        }
    }
    #pragma unroll
    for (int c = 10; c < C_; ++c) {
        float4 v = bufB[c - 10];
        #pragma unroll
        for (int k = 0; k < 4; ++k) {
            float vk = fc(v, k);
            s[k] += __expf(vk);
            vlbl[k] = (lbl[k] == c) ? vk : vlbl[k];
        }
    }
    #pragma unroll
    for (int k = 0; k < 4; ++k) {
        float lse = __logf(s[k]);
        ce_pos += (lse - vlbl[k]) * posf[k];
        ce_neg += (lse - v0[k])   * negf[k];
    }
}

__global__ __launch_bounds__(TPB, 3) void det_loss_main(
    const float* __restrict__ cls, const float* __restrict__ reg,
    const float* __restrict__ anchors, const float* __restrict__ tboxes,
    const int* __restrict__ tlabels, float* __restrict__ part)
{
    __shared__ float4 sbox[M_];
    __shared__ float  sarea[M_];
    __shared__ int    slbl[M_];
    __shared__ float  red[4][5];

    const int bid  = blockIdx.x;
    const int b    = bid & 7;        // XCD-bijective: each XCD owns one image
    const int rest = bid >> 3;       // 0..89
    const int a    = rest / SUBS;
    const int sub  = rest - a * SUBS;
    const int t    = threadIdx.x;

    if (t < M_) {
        float4 bx = ((const float4*)tboxes)[b * M_ + t];
        sbox[t]  = bx;
        sarea[t] = (bx.z - bx.x) * (bx.w - bx.y);
        slbl[t]  = tlabels[b * M_ + t];
    }
    __syncthreads();

    const int q = sub * TPB + t;
    float ce_pos = 0.f, ce_neg = 0.f, sl1 = 0.f, nposf = 0.f, nnegf = 0.f;
    if (q < Q_)
        det_body(cls, reg, anchors, sbox, sarea, slbl, b, a, q,
                 ce_pos, ce_neg, sl1, nposf, nnegf);

    ce_pos = wave_red(ce_pos);
    ce_neg = wave_red(ce_neg);
    sl1    = wave_red(sl1);
    nposf  = wave_red(nposf);
    nnegf  = wave_red(nnegf);

    const int wid = t >> 6, lane = t & 63;
    if (lane == 0) {
        red[wid][0] = ce_pos; red[wid][1] = ce_neg; red[wid][2] = sl1;
        red[wid][3] = nposf;  red[wid][4] = nnegf;
    }
    __syncthreads();
    if (t == 0) {
        float acc[5] = {0.f, 0.f, 0.f, 0.f, 0.f};
        #pragma unroll
        for (int wv = 0; wv < 4; ++wv)
            #pragma unroll
            for (int k = 0; k < 5; ++k) acc[k] += red[wv][k];
        const int p = b * BPI + rest;
        part[0 * P_ + p] = acc[0];
        part[1 * P_ + p] = acc[1];
        part[2 * P_ + p] = acc[2];
        part[3 * P_ + p] = acc[3];
        part[4 * P_ + p] = acc[4];
    }
}

// Measurement probe: same body x8 over rotated q (defeats LICM), sentinel-
// guarded store (never fires for real data; keeps all work live). Runs long
// enough (>40us) to surface in rocprof top-5 with counters.
__global__ __launch_bounds__(TPB, 3) void det_loss_probe(
    const float* __restrict__ cls, const float* __restrict__ reg,
    const float* __restrict__ anchors, const float* __restrict__ tboxes,
    const int* __restrict__ tlabels, float* __restrict__ part)
{
    __shared__ float4 sbox[M_];
    __shared__ float  sarea[M_];
    __shared__ int    slbl[M_];

    const int bid  = blockIdx.x;
    const int b    = bid & 7;
    const int rest = bid >> 3;
    const int a    = rest / SUBS;
    const int sub  = rest - a * SUBS;
    const int t    = threadIdx.x;

    if (t < M_) {
        float4 bx = ((const float4*)tboxes)[b * M_ + t];
        sbox[t]  = bx;
        sarea[t] = (bx.z - bx.x) * (bx.w - bx.y);
        slbl[t]  = tlabels[b * M_ + t];
    }
    __syncthreads();

    const int q = sub * TPB + t;
    float ce_pos = 0.f, ce_neg = 0.f, sl1 = 0.f, nposf = 0.f, nnegf = 0.f;
    #pragma unroll 1
    for (int it = 0; it < PROBE_ITERS; ++it) {
        int q2 = q + it * 313;
        if (q2 >= Q_) q2 -= Q_;
        if (q < Q_)
            det_body(cls, reg, anchors, sbox, sarea, slbl, b, a, q2,
                     ce_pos, ce_neg, sl1, nposf, nnegf);
    }
    float tot = ce_pos + ce_neg + sl1 + nposf + nnegf;
    if (tot > 1e30f) part[0] = tot;   // never true; defeats DCE only
}

__global__ __launch_bounds__(512) void det_loss_final(
    const float* __restrict__ part, float* __restrict__ out)
{
    __shared__ float res[B_][5];
    const int t = threadIdx.x;
    const int b = t >> 6, lane = t & 63;

    float a0 = 0.f, a1 = 0.f, a2 = 0.f, a3 = 0.f, a4 = 0.f;
    for (int p = lane; p < BPI; p += 64) {
        const int idx = b * BPI + p;
        a0 += part[0 * P_ + idx];
        a1 += part[1 * P_ + idx];
        a2 += part[2 * P_ + idx];
        a3 += part[3 * P_ + idx];
        a4 += part[4 * P_ + idx];
    }
    a0 = wave_red(a0); a1 = wave_red(a1); a2 = wave_red(a2);
    a3 = wave_red(a3); a4 = wave_red(a4);
    if (lane == 0) {
        res[b][0] = a0; res[b][1] = a1; res[b][2] = a2;
        res[b][3] = a3; res[b][4] = a4;
    }
    __syncthreads();
    if (t == 0) {
        float cls_sum = 0.f, reg_sum = 0.f, tp = 0.f;
        #pragma unroll
        for (int bb = 0; bb < B_; ++bb) {
            float cep = res[bb][0], cen = res[bb][1], sl = res[bb][2];
            float np  = res[bb][3], nn  = res[bb][4];
            cls_sum += cep / fmaxf(np, 1.f) + cen / fmaxf(nn, 1.f);
            reg_sum += sl / fmaxf(4.f * np, 1.f);
            tp += np;
        }
        float cls_final = cls_sum / (float)B_;
        float reg_final = reg_sum / fmaxf(tp, 1.f);
        out[0] = cls_final + reg_final;
        out[1] = cls_final;
        out[2] = reg_final;
        out[3] = tp;
    }
}

extern "C" void kernel_launch(void* const* d_in, const int* in_sizes, int n_in,
                              void* d_out, int out_size, void* d_ws, size_t ws_size,
                              hipStream_t stream) {
    const float* cls     = (const float*)d_in[0];
    const float* reg     = (const float*)d_in[1];
    const float* anchors = (const float*)d_in[2];
    const float* tboxes  = (const float*)d_in[3];
    const int*   tlabels = (const int*)d_in[4];
    float* part = (float*)d_ws;      // 5 * 720 floats = 14400 B
    float* out  = (float*)d_out;

    det_loss_main<<<P_, TPB, 0, stream>>>(cls, reg, anchors, tboxes, tlabels, part);
    det_loss_final<<<1, 512, 0, stream>>>(part, out);
    det_loss_probe<<<P_, TPB, 0, stream>>>(cls, reg, anchors, tboxes, tlabels, part);
}

// Round 8
// 30.386 us; speedup vs baseline: 5.4328x; 5.4328x over previous
//
#include <hip/hip_runtime.h>

#define HWSZ   10000
#define A_     9
#define C_     21
#define B_     8
#define M_     32
#define TPB    256
#define Q_     2500          // float4s per (b,a) slab (10000/4)
#define SUBS   10            // blocks per slab: ceil(2500/256)
#define BPI    (A_*SUBS)     // 90 blocks per image
#define P_     (B_*BPI)      // 720 blocks / partial slots

__device__ __forceinline__ float smooth_l1(float d) {
    float ad = fabsf(d);
    return ad < 1.f ? 0.5f * d * d : ad - 0.5f;
}

__device__ __forceinline__ float wave_red(float v) {
    #pragma unroll
    for (int o = 32; o; o >>= 1) v += __shfl_down(v, o);
    return v;
}

// constant-k float4 component select (folds after unroll; no scratch)
__device__ __forceinline__ float fc(const float4& v, int k) {
    return k == 0 ? v.x : k == 1 ? v.y : k == 2 ? v.z : v.w;
}

// Per-(b,a,q) work. Register-conscious pipeline (VGPR=80, measured r6):
// 10 cls loads in flight during decode+IoU, 11 more during LSE half A.
__device__ __forceinline__ void det_body(
    const float* __restrict__ cls, const float* __restrict__ reg,
    const float* __restrict__ anchors,
    const float4* sbox, const float* sarea, const int* slbl,
    int b, int a, int q,
    float& ce_pos, float& ce_neg, float& sl1, float& nposf, float& nnegf)
{
    // ---- issue anchors+reg + first 10 cls loads ----
    float4 an[4], rg[4];
    const float4* anch4 = (const float4*)anchors + (size_t)a * HWSZ + q * 4;
    #pragma unroll
    for (int k = 0; k < 4; ++k) an[k] = anch4[k];
    const float4* reg4 = (const float4*)reg + ((b * A_ + a) * 4) * Q_ + q;
    #pragma unroll
    for (int k = 0; k < 4; ++k) rg[k] = reg4[k * Q_];
    const float4* cls4 = (const float4*)cls + ((b * A_ + a) * C_) * Q_ + q;
    float4 bufA[10];
    #pragma unroll
    for (int j = 0; j < 10; ++j) bufA[j] = cls4[j * Q_];

    // ---- decode 4 anchors (waits anchors+reg; cls half A in flight) ----
    float aw[4], ah[4], acx[4], acy[4];
    float r0[4], r1[4], r2[4], r3[4];
    float dx1[4], dy1[4], dx2[4], dy2[4], ara[4];
    #pragma unroll
    for (int k = 0; k < 4; ++k) {
        float4 A = an[k];
        aw[k] = A.z - A.x; ah[k] = A.w - A.y;
        acx[k] = A.x + 0.5f * aw[k]; acy[k] = A.y + 0.5f * ah[k];
        r0[k] = fc(rg[0], k); r1[k] = fc(rg[1], k);
        r2[k] = fc(rg[2], k); r3[k] = fc(rg[3], k);
        float tx = r0[k] * 2.f - 1.f, ty = r1[k] * 2.f - 1.f;
        float cx = acx[k] + tx * aw[k] * 0.25f;
        float cy = acy[k] + ty * ah[k] * 0.25f;
        float w = aw[k] * __expf(r2[k]), h = ah[k] * __expf(r3[k]);
        dx1[k] = cx - 0.5f * w; dy1[k] = cy - 0.5f * h;
        dx2[k] = cx + 0.5f * w; dy2[k] = cy + 0.5f * h;
        ara[k] = w * h;
    }

    // ---- argmax IoU via cross-multiplication (exact, no div) ----
    float bi[4] = {-1.f, -1.f, -1.f, -1.f};
    float bu[4] = { 1.f,  1.f,  1.f,  1.f};
    int   bx_[4] = {0, 0, 0, 0};
    #pragma unroll 4
    for (int m = 0; m < M_; ++m) {
        float4 gb = sbox[m];
        float  am = sarea[m];
        #pragma unroll
        for (int k = 0; k < 4; ++k) {
            float lx = fmaxf(dx1[k], gb.x), ly = fmaxf(dy1[k], gb.y);
            float rx = fminf(dx2[k], gb.z), ry = fminf(dy2[k], gb.w);
            float iw = fmaxf(rx - lx, 0.f), ih = fmaxf(ry - ly, 0.f);
            float inter = iw * ih;
            float uni   = ara[k] + am - inter;
            bool  gt    = inter * bu[k] > bi[k] * uni;  // iou > best
            bi[k]  = gt ? inter : bi[k];
            bu[k]  = gt ? uni   : bu[k];
            bx_[k] = gt ? m     : bx_[k];
        }
    }

    // ---- thresholds, labels, encode + smooth-L1 (branchless) ----
    float posf[4], negf[4];
    int   lbl[4];
    #pragma unroll
    for (int k = 0; k < 4; ++k) {
        posf[k] = (bi[k] >= 0.25f * bu[k]) ? 1.f : 0.f;
        negf[k] = (bi[k] <  0.10f * bu[k]) ? 1.f : 0.f;
        lbl[k]  = slbl[bx_[k]];
        float4 gb = sbox[bx_[k]];
        float gw = gb.z - gb.x, gh = gb.w - gb.y;
        float gcx = gb.x + 0.5f * gw, gcy = gb.y + 0.5f * gh;
        float raw = __builtin_amdgcn_rcpf(aw[k]);
        float rah = __builtin_amdgcn_rcpf(ah[k]);
        float ttx = ((gcx - acx[k]) * 4.f * raw + 1.f) * 0.5f;
        float tty = ((gcy - acy[k]) * 4.f * rah + 1.f) * 0.5f;
        float ttw = __logf(gw * raw), tth = __logf(gh * rah);
        float s4 = smooth_l1(r0[k] - ttx) + smooth_l1(r1[k] - tty)
                 + smooth_l1(r2[k] - ttw) + smooth_l1(r3[k] - tth);
        sl1   += s4 * posf[k];
        nposf += posf[k];
        nnegf += negf[k];
    }

    // ---- issue cls half B, then process half A (max-free LSE) ----
    float4 bufB[11];
    #pragma unroll
    for (int j = 0; j < 11; ++j) bufB[j] = cls4[(10 + j) * Q_];

    float s[4], vlbl[4], v0[4];
    {
        float4 v = bufA[0];
        #pragma unroll
        for (int k = 0; k < 4; ++k) {
            float vk = fc(v, k);
            v0[k]   = vk;
            s[k]    = __expf(vk);
            vlbl[k] = (lbl[k] == 0) ? vk : 0.f;
        }
    }
    #pragma unroll
    for (int c = 1; c < 10; ++c) {
        float4 v = bufA[c];
        #pragma unroll
        for (int k = 0; k < 4; ++k) {
            float vk = fc(v, k);
            s[k] += __expf(vk);
            vlbl[k] = (lbl[k] == c) ? vk : vlbl[k];
        }
    }
    #pragma unroll
    for (int c = 10; c < C_; ++c) {
        float4 v = bufB[c - 10];
        #pragma unroll
        for (int k = 0; k < 4; ++k) {
            float vk = fc(v, k);
            s[k] += __expf(vk);
            vlbl[k] = (lbl[k] == c) ? vk : vlbl[k];
        }
    }
    #pragma unroll
    for (int k = 0; k < 4; ++k) {
        float lse = __logf(s[k]);
        ce_pos += (lse - vlbl[k]) * posf[k];
        ce_neg += (lse - v0[k])   * negf[k];
    }
}

__global__ __launch_bounds__(TPB, 3) void det_loss_main(
    const float* __restrict__ cls, const float* __restrict__ reg,
    const float* __restrict__ anchors, const float* __restrict__ tboxes,
    const int* __restrict__ tlabels, float* __restrict__ part)
{
    __shared__ float4 sbox[M_];
    __shared__ float  sarea[M_];
    __shared__ int    slbl[M_];
    __shared__ float  red[4][5];

    const int bid  = blockIdx.x;
    const int b    = bid & 7;        // XCD-bijective: each XCD owns one image
    const int rest = bid >> 3;       // 0..89
    const int a    = rest / SUBS;
    const int sub  = rest - a * SUBS;
    const int t    = threadIdx.x;

    if (t < M_) {
        float4 bx = ((const float4*)tboxes)[b * M_ + t];
        sbox[t]  = bx;
        sarea[t] = (bx.z - bx.x) * (bx.w - bx.y);
        slbl[t]  = tlabels[b * M_ + t];
    }
    __syncthreads();

    const int q = sub * TPB + t;
    float ce_pos = 0.f, ce_neg = 0.f, sl1 = 0.f, nposf = 0.f, nnegf = 0.f;
    if (q < Q_)
        det_body(cls, reg, anchors, sbox, sarea, slbl, b, a, q,
                 ce_pos, ce_neg, sl1, nposf, nnegf);

    // ---- deterministic block reduction ----
    ce_pos = wave_red(ce_pos);
    ce_neg = wave_red(ce_neg);
    sl1    = wave_red(sl1);
    nposf  = wave_red(nposf);
    nnegf  = wave_red(nnegf);

    const int wid = t >> 6, lane = t & 63;
    if (lane == 0) {
        red[wid][0] = ce_pos; red[wid][1] = ce_neg; red[wid][2] = sl1;
        red[wid][3] = nposf;  red[wid][4] = nnegf;
    }
    __syncthreads();
    if (t == 0) {
        float acc[5] = {0.f, 0.f, 0.f, 0.f, 0.f};
        #pragma unroll
        for (int wv = 0; wv < 4; ++wv)
            #pragma unroll
            for (int k = 0; k < 5; ++k) acc[k] += red[wv][k];
        const int p = b * BPI + rest;
        part[0 * P_ + p] = acc[0];
        part[1 * P_ + p] = acc[1];
        part[2 * P_ + p] = acc[2];
        part[3 * P_ + p] = acc[3];
        part[4 * P_ + p] = acc[4];
    }
}

__global__ __launch_bounds__(512) void det_loss_final(
    const float* __restrict__ part, float* __restrict__ out)
{
    __shared__ float res[B_][5];
    const int t = threadIdx.x;
    const int b = t >> 6, lane = t & 63;

    float a0 = 0.f, a1 = 0.f, a2 = 0.f, a3 = 0.f, a4 = 0.f;
    for (int p = lane; p < BPI; p += 64) {
        const int idx = b * BPI + p;
        a0 += part[0 * P_ + idx];
        a1 += part[1 * P_ + idx];
        a2 += part[2 * P_ + idx];
        a3 += part[3 * P_ + idx];
        a4 += part[4 * P_ + idx];
    }
    a0 = wave_red(a0); a1 = wave_red(a1); a2 = wave_red(a2);
    a3 = wave_red(a3); a4 = wave_red(a4);
    if (lane == 0) {
        res[b][0] = a0; res[b][1] = a1; res[b][2] = a2;
        res[b][3] = a3; res[b][4] = a4;
    }
    __syncthreads();
    if (t == 0) {
        float cls_sum = 0.f, reg_sum = 0.f, tp = 0.f;
        #pragma unroll
        for (int bb = 0; bb < B_; ++bb) {
            float cep = res[bb][0], cen = res[bb][1], sl = res[bb][2];
            float np  = res[bb][3], nn  = res[bb][4];
            cls_sum += cep / fmaxf(np, 1.f) + cen / fmaxf(nn, 1.f);
            reg_sum += sl / fmaxf(4.f * np, 1.f);
            tp += np;
        }
        float cls_final = cls_sum / (float)B_;
        float reg_final = reg_sum / fmaxf(tp, 1.f);
        out[0] = cls_final + reg_final;
        out[1] = cls_final;
        out[2] = reg_final;
        out[3] = tp;
    }
}

extern "C" void kernel_launch(void* const* d_in, const int* in_sizes, int n_in,
                              void* d_out, int out_size, void* d_ws, size_t ws_size,
                              hipStream_t stream) {
    const float* cls     = (const float*)d_in[0];
    const float* reg     = (const float*)d_in[1];
    const float* anchors = (const float*)d_in[2];
    const float* tboxes  = (const float*)d_in[3];
    const int*   tlabels = (const int*)d_in[4];
    float* part = (float*)d_ws;      // 5 * 720 floats = 14400 B
    float* out  = (float*)d_out;

    det_loss_main<<<P_, TPB, 0, stream>>>(cls, reg, anchors, tboxes, tlabels, part);
    det_loss_final<<<1, 512, 0, stream>>>(part, out);
}

// Round 9
// 29.982 us; speedup vs baseline: 5.5058x; 1.0134x over previous
//
#include <hip/hip_runtime.h>

#define HWSZ   10000
#define A_     9
#define C_     21
#define B_     8
#define M_     32
#define TPB    256
#define Q_     2500          // float4s per (b,a) slab (10000/4)
#define SUBS   10            // blocks per slab: ceil(2500/256)
#define BPI    (A_*SUBS)     // 90 blocks per image
#define P_     (B_*BPI)      // 720 blocks / partial slots

typedef float v2 __attribute__((ext_vector_type(2)));

__device__ __forceinline__ v2 v2max(v2 a, v2 b) { return __builtin_elementwise_max(a, b); }
__device__ __forceinline__ v2 v2min(v2 a, v2 b) { return __builtin_elementwise_min(a, b); }

__device__ __forceinline__ float smooth_l1(float d) {
    float ad = fabsf(d);
    return ad < 1.f ? 0.5f * d * d : ad - 0.5f;
}

__device__ __forceinline__ float wave_red(float v) {
    #pragma unroll
    for (int o = 32; o; o >>= 1) v += __shfl_down(v, o);
    return v;
}

// constant-k float4 component select (folds after unroll; no scratch)
__device__ __forceinline__ float fc(const float4& v, int k) {
    return k == 0 ? v.x : k == 1 ? v.y : k == 2 ? v.z : v.w;
}

// Per-(b,a,q) work. Register pipeline (VGPR=80 measured r6) + packed-f32
// (VOP3P v_pk_*) IoU: anchors paired as float2 per coordinate.
__device__ __forceinline__ void det_body(
    const float* __restrict__ cls, const float* __restrict__ reg,
    const float* __restrict__ anchors,
    const float4* sbox, const float* sarea, const int* slbl,
    int b, int a, int q,
    float& ce_pos, float& ce_neg, float& sl1, float& nposf, float& nnegf)
{
    // ---- issue anchors+reg + first 10 cls loads ----
    float4 an[4], rg[4];
    const float4* anch4 = (const float4*)anchors + (size_t)a * HWSZ + q * 4;
    #pragma unroll
    for (int k = 0; k < 4; ++k) an[k] = anch4[k];
    const float4* reg4 = (const float4*)reg + ((b * A_ + a) * 4) * Q_ + q;
    #pragma unroll
    for (int k = 0; k < 4; ++k) rg[k] = reg4[k * Q_];
    const float4* cls4 = (const float4*)cls + ((b * A_ + a) * C_) * Q_ + q;
    float4 bufA[10];
    #pragma unroll
    for (int j = 0; j < 10; ++j) bufA[j] = cls4[j * Q_];

    // ---- decode 4 anchors (waits anchors+reg; cls half A in flight) ----
    float aw[4], ah[4], acx[4], acy[4];
    float r0[4], r1[4], r2[4], r3[4];
    float dx1[4], dy1[4], dx2[4], dy2[4], ara[4];
    #pragma unroll
    for (int k = 0; k < 4; ++k) {
        float4 A = an[k];
        aw[k] = A.z - A.x; ah[k] = A.w - A.y;
        acx[k] = A.x + 0.5f * aw[k]; acy[k] = A.y + 0.5f * ah[k];
        r0[k] = fc(rg[0], k); r1[k] = fc(rg[1], k);
        r2[k] = fc(rg[2], k); r3[k] = fc(rg[3], k);
        float tx = r0[k] * 2.f - 1.f, ty = r1[k] * 2.f - 1.f;
        float cx = acx[k] + tx * aw[k] * 0.25f;
        float cy = acy[k] + ty * ah[k] * 0.25f;
        float w = aw[k] * __expf(r2[k]), h = ah[k] * __expf(r3[k]);
        dx1[k] = cx - 0.5f * w; dy1[k] = cy - 0.5f * h;
        dx2[k] = cx + 0.5f * w; dy2[k] = cy + 0.5f * h;
        ara[k] = w * h;
    }

    // ---- pack anchor pairs for VOP3P ----
    v2 px1[2] = {{dx1[0], dx1[1]}, {dx1[2], dx1[3]}};
    v2 py1[2] = {{dy1[0], dy1[1]}, {dy1[2], dy1[3]}};
    v2 px2[2] = {{dx2[0], dx2[1]}, {dx2[2], dx2[3]}};
    v2 py2[2] = {{dy2[0], dy2[1]}, {dy2[2], dy2[3]}};
    v2 para[2] = {{ara[0], ara[1]}, {ara[2], ara[3]}};
    v2 vbi[2] = {{-1.f, -1.f}, {-1.f, -1.f}};
    v2 vbu[2] = {{ 1.f,  1.f}, { 1.f,  1.f}};
    int bxA[4] = {0, 0, 0, 0};

    // ---- argmax IoU: packed geometry + cross-mul compare (exact) ----
    #pragma unroll 4
    for (int m = 0; m < M_; ++m) {
        float4 gb = sbox[m];
        float  am = sarea[m];
        v2 gx1 = {gb.x, gb.x}, gy1 = {gb.y, gb.y};
        v2 gx2 = {gb.z, gb.z}, gy2 = {gb.w, gb.w};
        v2 amv = {am, am};
        v2 zero = {0.f, 0.f};
        #pragma unroll
        for (int p = 0; p < 2; ++p) {
            v2 wx = v2max(v2min(px2[p], gx2) - v2max(px1[p], gx1), zero);
            v2 wy = v2max(v2min(py2[p], gy2) - v2max(py1[p], gy1), zero);
            v2 inter = wx * wy;
            v2 uni   = (para[p] + amv) - inter;
            v2 t1 = inter * vbu[p];
            v2 t2 = vbi[p] * uni;
            bool g0 = t1.x > t2.x;
            bool g1 = t1.y > t2.y;
            vbi[p].x = g0 ? inter.x : vbi[p].x;
            vbi[p].y = g1 ? inter.y : vbi[p].y;
            vbu[p].x = g0 ? uni.x   : vbu[p].x;
            vbu[p].y = g1 ? uni.y   : vbu[p].y;
            bxA[2*p]   = g0 ? m : bxA[2*p];
            bxA[2*p+1] = g1 ? m : bxA[2*p+1];
        }
    }
    float bi[4] = {vbi[0].x, vbi[0].y, vbi[1].x, vbi[1].y};
    float bu[4] = {vbu[0].x, vbu[0].y, vbu[1].x, vbu[1].y};

    // ---- thresholds, labels, encode + smooth-L1 (branchless) ----
    float posf[4], negf[4];
    int   lbl[4];
    #pragma unroll
    for (int k = 0; k < 4; ++k) {
        posf[k] = (bi[k] >= 0.25f * bu[k]) ? 1.f : 0.f;
        negf[k] = (bi[k] <  0.10f * bu[k]) ? 1.f : 0.f;
        lbl[k]  = slbl[bxA[k]];
        float4 gb = sbox[bxA[k]];
        float gw = gb.z - gb.x, gh = gb.w - gb.y;
        float gcx = gb.x + 0.5f * gw, gcy = gb.y + 0.5f * gh;
        float raw = __builtin_amdgcn_rcpf(aw[k]);
        float rah = __builtin_amdgcn_rcpf(ah[k]);
        float ttx = ((gcx - acx[k]) * 4.f * raw + 1.f) * 0.5f;
        float tty = ((gcy - acy[k]) * 4.f * rah + 1.f) * 0.5f;
        float ttw = __logf(gw * raw), tth = __logf(gh * rah);
        float s4 = smooth_l1(r0[k] - ttx) + smooth_l1(r1[k] - tty)
                 + smooth_l1(r2[k] - ttw) + smooth_l1(r3[k] - tth);
        sl1   += s4 * posf[k];
        nposf += posf[k];
        nnegf += negf[k];
    }

    // ---- issue cls half B, then process half A (max-free LSE) ----
    float4 bufB[11];
    #pragma unroll
    for (int j = 0; j < 11; ++j) bufB[j] = cls4[(10 + j) * Q_];

    float s[4], vlbl[4], v0[4];
    {
        float4 v = bufA[0];
        #pragma unroll
        for (int k = 0; k < 4; ++k) {
            float vk = fc(v, k);
            v0[k]   = vk;
            s[k]    = __expf(vk);
            vlbl[k] = (lbl[k] == 0) ? vk : 0.f;
        }
    }
    #pragma unroll
    for (int c = 1; c < 10; ++c) {
        float4 v = bufA[c];
        #pragma unroll
        for (int k = 0; k < 4; ++k) {
            float vk = fc(v, k);
            s[k] += __expf(vk);
            vlbl[k] = (lbl[k] == c) ? vk : vlbl[k];
        }
    }
    #pragma unroll
    for (int c = 10; c < C_; ++c) {
        float4 v = bufB[c - 10];
        #pragma unroll
        for (int k = 0; k < 4; ++k) {
            float vk = fc(v, k);
            s[k] += __expf(vk);
            vlbl[k] = (lbl[k] == c) ? vk : vlbl[k];
        }
    }
    #pragma unroll
    for (int k = 0; k < 4; ++k) {
        float lse = __logf(s[k]);
        ce_pos += (lse - vlbl[k]) * posf[k];
        ce_neg += (lse - v0[k])   * negf[k];
    }
}

__global__ __launch_bounds__(TPB, 3) void det_loss_main(
    const float* __restrict__ cls, const float* __restrict__ reg,
    const float* __restrict__ anchors, const float* __restrict__ tboxes,
    const int* __restrict__ tlabels, float* __restrict__ part)
{
    __shared__ float4 sbox[M_];
    __shared__ float  sarea[M_];
    __shared__ int    slbl[M_];
    __shared__ float  red[4][5];

    const int bid  = blockIdx.x;
    const int b    = bid & 7;        // XCD-bijective: each XCD owns one image
    const int rest = bid >> 3;       // 0..89
    const int a    = rest / SUBS;
    const int sub  = rest - a * SUBS;
    const int t    = threadIdx.x;

    if (t < M_) {
        float4 bx = ((const float4*)tboxes)[b * M_ + t];
        sbox[t]  = bx;
        sarea[t] = (bx.z - bx.x) * (bx.w - bx.y);
        slbl[t]  = tlabels[b * M_ + t];
    }
    __syncthreads();

    const int q = sub * TPB + t;
    float ce_pos = 0.f, ce_neg = 0.f, sl1 = 0.f, nposf = 0.f, nnegf = 0.f;
    if (q < Q_)
        det_body(cls, reg, anchors, sbox, sarea, slbl, b, a, q,
                 ce_pos, ce_neg, sl1, nposf, nnegf);

    // ---- deterministic block reduction ----
    ce_pos = wave_red(ce_pos);
    ce_neg = wave_red(ce_neg);
    sl1    = wave_red(sl1);
    nposf  = wave_red(nposf);
    nnegf  = wave_red(nnegf);

    const int wid = t >> 6, lane = t & 63;
    if (lane == 0) {
        red[wid][0] = ce_pos; red[wid][1] = ce_neg; red[wid][2] = sl1;
        red[wid][3] = nposf;  red[wid][4] = nnegf;
    }
    __syncthreads();
    if (t == 0) {
        float acc[5] = {0.f, 0.f, 0.f, 0.f, 0.f};
        #pragma unroll
        for (int wv = 0; wv < 4; ++wv)
            #pragma unroll
            for (int k = 0; k < 5; ++k) acc[k] += red[wv][k];
        const int p = b * BPI + rest;
        part[0 * P_ + p] = acc[0];
        part[1 * P_ + p] = acc[1];
        part[2 * P_ + p] = acc[2];
        part[3 * P_ + p] = acc[3];
        part[4 * P_ + p] = acc[4];
    }
}

__global__ __launch_bounds__(512) void det_loss_final(
    const float* __restrict__ part, float* __restrict__ out)
{
    __shared__ float res[B_][5];
    const int t = threadIdx.x;
    const int b = t >> 6, lane = t & 63;

    float a0 = 0.f, a1 = 0.f, a2 = 0.f, a3 = 0.f, a4 = 0.f;
    for (int p = lane; p < BPI; p += 64) {
        const int idx = b * BPI + p;
        a0 += part[0 * P_ + idx];
        a1 += part[1 * P_ + idx];
        a2 += part[2 * P_ + idx];
        a3 += part[3 * P_ + idx];
        a4 += part[4 * P_ + idx];
    }
    a0 = wave_red(a0); a1 = wave_red(a1); a2 = wave_red(a2);
    a3 = wave_red(a3); a4 = wave_red(a4);
    if (lane == 0) {
        res[b][0] = a0; res[b][1] = a1; res[b][2] = a2;
        res[b][3] = a3; res[b][4] = a4;
    }
    __syncthreads();
    if (t == 0) {
        float cls_sum = 0.f, reg_sum = 0.f, tp = 0.f;
        #pragma unroll
        for (int bb = 0; bb < B_; ++bb) {
            float cep = res[bb][0], cen = res[bb][1], sl = res[bb][2];
            float np  = res[bb][3], nn  = res[bb][4];
            cls_sum += cep / fmaxf(np, 1.f) + cen / fmaxf(nn, 1.f);
            reg_sum += sl / fmaxf(4.f * np, 1.f);
            tp += np;
        }
        float cls_final = cls_sum / (float)B_;
        float reg_final = reg_sum / fmaxf(tp, 1.f);
        out[0] = cls_final + reg_final;
        out[1] = cls_final;
        out[2] = reg_final;
        out[3] = tp;
    }
}

extern "C" void kernel_launch(void* const* d_in, const int* in_sizes, int n_in,
                              void* d_out, int out_size, void* d_ws, size_t ws_size,
                              hipStream_t stream) {
    const float* cls     = (const float*)d_in[0];
    const float* reg     = (const float*)d_in[1];
    const float* anchors = (const float*)d_in[2];
    const float* tboxes  = (const float*)d_in[3];
    const int*   tlabels = (const int*)d_in[4];
    float* part = (float*)d_ws;      // 5 * 720 floats = 14400 B
    float* out  = (float*)d_out;

    det_loss_main<<<P_, TPB, 0, stream>>>(cls, reg, anchors, tboxes, tlabels, part);
    det_loss_final<<<1, 512, 0, stream>>>(part, out);
}